// Round 1
// baseline (290.994 us; speedup 1.0000x reference)
//
#include <hip/hip_runtime.h>
#include <hip/hip_bf16.h>

// ScaledDotProductAttention: N=M=8192, DK=DV=256, fp32 in/out.
// Strategy: bf16 MFMA flash attention. Pre-convert Q(*1/16),K -> bf16,
// V -> bf16 transposed [256][8192]. Main kernel: 256 blocks x 4 waves,
// QBLK=32 (2 q-tiles of 16 rows), KV tile 64 staged in LDS, wave pairs
// split the KV tile, online softmax per wave, pairwise merge at end.

typedef __attribute__((ext_vector_type(4))) float floatx4;
typedef __attribute__((ext_vector_type(8))) short short8;

union S8u { short8 v; unsigned short u[8]; };

__device__ __forceinline__ unsigned short f2bf(float f) {
    unsigned int u = __builtin_bit_cast(unsigned int, f);
    unsigned int r = u + 0x7fffu + ((u >> 16) & 1u);   // RNE
    return (unsigned short)(r >> 16);
}

// ---------------- conversion kernels ----------------

__global__ void cvt_bf16_kernel(const float* __restrict__ in,
                                unsigned short* __restrict__ out,
                                float scale, int n8) {
    int i = blockIdx.x * blockDim.x + threadIdx.x;
    if (i >= n8) return;
    const float4* p = reinterpret_cast<const float4*>(in) + (size_t)i * 2;
    float4 a = p[0], b = p[1];
    S8u r;
    r.u[0] = f2bf(a.x * scale); r.u[1] = f2bf(a.y * scale);
    r.u[2] = f2bf(a.z * scale); r.u[3] = f2bf(a.w * scale);
    r.u[4] = f2bf(b.x * scale); r.u[5] = f2bf(b.y * scale);
    r.u[6] = f2bf(b.z * scale); r.u[7] = f2bf(b.w * scale);
    *reinterpret_cast<short8*>(out + (size_t)i * 8) = r.v;
}

// V [8192][256] f32 -> Vt [256][8192] bf16, 64x64 tiles
__global__ void transpose_v_kernel(const float* __restrict__ V,
                                   unsigned short* __restrict__ Vt) {
    __shared__ unsigned short T[64][72];   // stride 144B (16B-aligned)
    const int kv0 = blockIdx.x * 64;
    const int v0  = blockIdx.y * 64;
    const int tid = threadIdx.x;           // 256
#pragma unroll
    for (int it = 0; it < 4; ++it) {
        int flat = it * 256 + tid;         // 0..1023
        int r  = flat >> 4;                // kv row 0..63
        int c4 = (flat & 15) * 4;          // v col
        float4 f = *reinterpret_cast<const float4*>(
            V + (size_t)(kv0 + r) * 256 + v0 + c4);
        T[c4 + 0][r] = f2bf(f.x);
        T[c4 + 1][r] = f2bf(f.y);
        T[c4 + 2][r] = f2bf(f.z);
        T[c4 + 3][r] = f2bf(f.w);
    }
    __syncthreads();
#pragma unroll
    for (int it = 0; it < 2; ++it) {
        int flat = it * 256 + tid;         // 0..511
        int r  = flat >> 3;                // v row 0..63
        int c8 = (flat & 7) * 8;           // kv col chunk
        short8 v8 = *reinterpret_cast<const short8*>(&T[r][c8]);
        *reinterpret_cast<short8*>(Vt + (size_t)(v0 + r) * 8192 + kv0 + c8) = v8;
    }
}

// ---------------- main attention kernel ----------------

#define KSTRIDE 264   // K_lds row stride (elems): 528B, 2-way bank alias (free)
#define VSTRIDE 80    // Vt_lds row stride: 160B
#define PSTRIDE 80

__global__ __launch_bounds__(256, 1)
void attn_kernel(const unsigned short* __restrict__ Qb,   // [8192][256], pre-scaled
                 const unsigned short* __restrict__ Kb,   // [8192][256]
                 const unsigned short* __restrict__ Vt,   // [256][8192]
                 float* __restrict__ out) {               // [8192][256]
    __shared__ __align__(16) unsigned short K_lds[64][KSTRIDE];    // 33792 B
    __shared__ __align__(16) unsigned short Vt_lds[256][VSTRIDE];  // 40960 B
    __shared__ __align__(16) unsigned short P_lds[4][16][PSTRIDE]; // 10240 B
    __shared__ float mergeM[2][16], mergeL[2][16];

    const int tid  = threadIdx.x;
    const int lane = tid & 63;
    const int w    = tid >> 6;      // wave 0..3
    const int qt   = w >> 1;        // q sub-tile 0/1
    const int kvh  = w & 1;         // kv half 0/1
    const int l15  = lane & 15;
    const int lg   = lane >> 4;     // 0..3
    const int qbase = blockIdx.x * 32 + qt * 16;
    const int ko   = kvh * 32;      // wave's kv offset within 64-tile

    // Q fragments in registers: row qbase+l15, d = s*32 + lg*8 + e
    short8 qf[8];
    {
        const unsigned short* qrow = Qb + (size_t)(qbase + l15) * 256 + lg * 8;
#pragma unroll
        for (int s = 0; s < 8; ++s)
            qf[s] = *reinterpret_cast<const short8*>(qrow + s * 32);
    }

    floatx4 o[16];
#pragma unroll
    for (int v = 0; v < 16; ++v) o[v] = floatx4{0.f, 0.f, 0.f, 0.f};
    float m_run[4], l_run[4];
#pragma unroll
    for (int r = 0; r < 4; ++r) { m_run[r] = -1e30f; l_run[r] = 0.f; }

    for (int kv0 = 0; kv0 < 8192; kv0 += 64) {
        // ---- stage K tile [64][256] ----
#pragma unroll
        for (int it = 0; it < 8; ++it) {
            int flat = it * 256 + tid;            // 0..2047
            int row = flat >> 5;                  // 0..63
            int c   = (flat & 31) * 8;            // elem col
            short8 vle = *reinterpret_cast<const short8*>(
                Kb + (size_t)(kv0 + row) * 256 + c);
            *reinterpret_cast<short8*>(&K_lds[row][c]) = vle;
        }
        // ---- stage Vt tile [256][64] ----
#pragma unroll
        for (int it = 0; it < 8; ++it) {
            int flat = it * 256 + tid;
            int row = flat >> 3;                  // 0..255
            int c8  = (flat & 7) * 8;             // 0..56
            short8 vle = *reinterpret_cast<const short8*>(
                Vt + (size_t)row * 8192 + kv0 + c8);
            *reinterpret_cast<short8*>(&Vt_lds[row][c8]) = vle;
        }
        __syncthreads();

        // ---- QK^T: S[16 x 32] for this wave's kv half ----
        floatx4 s0 = floatx4{0.f, 0.f, 0.f, 0.f};
        floatx4 s1 = floatx4{0.f, 0.f, 0.f, 0.f};
#pragma unroll
        for (int ss = 0; ss < 8; ++ss) {
            short8 b0 = *reinterpret_cast<const short8*>(
                &K_lds[ko + l15][ss * 32 + lg * 8]);
            short8 b1 = *reinterpret_cast<const short8*>(
                &K_lds[ko + 16 + l15][ss * 32 + lg * 8]);
            s0 = __builtin_amdgcn_mfma_f32_16x16x32_bf16(qf[ss], b0, s0, 0, 0, 0);
            s1 = __builtin_amdgcn_mfma_f32_16x16x32_bf16(qf[ss], b1, s1, 0, 0, 0);
        }

        // ---- online softmax (rows spread: row = lg*4+r, col = j*16+l15) ----
        float al[4];
#pragma unroll
        for (int r = 0; r < 4; ++r) {
            float v = fmaxf(s0[r], s1[r]);
            v = fmaxf(v, __shfl_xor(v, 8));
            v = fmaxf(v, __shfl_xor(v, 4));
            v = fmaxf(v, __shfl_xor(v, 2));
            v = fmaxf(v, __shfl_xor(v, 1));
            float mn = fmaxf(m_run[r], v);
            al[r] = __expf(m_run[r] - mn);
            m_run[r] = mn;
            float p0 = __expf(s0[r] - mn);
            float p1 = __expf(s1[r] - mn);
            s0[r] = p0; s1[r] = p1;
            float rs = p0 + p1;
            rs += __shfl_xor(rs, 8);
            rs += __shfl_xor(rs, 4);
            rs += __shfl_xor(rs, 2);
            rs += __shfl_xor(rs, 1);
            l_run[r] = l_run[r] * al[r] + rs;
        }
        // rescale accumulators
#pragma unroll
        for (int v = 0; v < 16; ++v) {
#pragma unroll
            for (int r = 0; r < 4; ++r) o[v][r] *= al[r];
        }
        // ---- P -> LDS (bf16), transpose to A-fragment layout ----
#pragma unroll
        for (int r = 0; r < 4; ++r) {
            P_lds[w][lg * 4 + r][l15]      = f2bf(s0[r]);
            P_lds[w][lg * 4 + r][16 + l15] = f2bf(s1[r]);
        }
        // ---- PV: O += P[16x32] * V[32x256] ----
        short8 pf = *reinterpret_cast<const short8*>(&P_lds[w][l15][lg * 8]);
#pragma unroll
        for (int v = 0; v < 16; ++v) {
            short8 b = *reinterpret_cast<const short8*>(
                &Vt_lds[v * 16 + l15][ko + lg * 8]);
            o[v] = __builtin_amdgcn_mfma_f32_16x16x32_bf16(pf, b, o[v], 0, 0, 0);
        }
        __syncthreads();
    }

    // ---- merge wave pairs (kvh=0 merges kvh=1), reuse K_lds as f32 scratch ----
    float* oB = reinterpret_cast<float*>(&K_lds[0][0]) + qt * (16 * 256);
    if (kvh == 1) {
#pragma unroll
        for (int v = 0; v < 16; ++v) {
#pragma unroll
            for (int r = 0; r < 4; ++r)
                oB[(lg * 4 + r) * 256 + v * 16 + l15] = o[v][r];
        }
        if (l15 == 0) {
#pragma unroll
            for (int r = 0; r < 4; ++r) {
                mergeM[qt][lg * 4 + r] = m_run[r];
                mergeL[qt][lg * 4 + r] = l_run[r];
            }
        }
    }
    __syncthreads();
    if (kvh == 0) {
#pragma unroll
        for (int r = 0; r < 4; ++r) {
            int row = lg * 4 + r;
            float mB = mergeM[qt][row], lB = mergeL[qt][row];
            float m  = fmaxf(m_run[r], mB);
            float aA = __expf(m_run[r] - m);
            float aB = __expf(mB - m);
            float linv = 1.0f / (l_run[r] * aA + lB * aB);
#pragma unroll
            for (int v = 0; v < 16; ++v) {
                float val = (o[v][r] * aA + oB[row * 256 + v * 16 + l15] * aB) * linv;
                out[(size_t)(qbase + row) * 256 + v * 16 + l15] = val;
            }
        }
    }
}

// ---------------- launcher ----------------

extern "C" void kernel_launch(void* const* d_in, const int* in_sizes, int n_in,
                              void* d_out, int out_size, void* d_ws, size_t ws_size,
                              hipStream_t stream) {
    const float* Q = (const float*)d_in[0];
    const float* K = (const float*)d_in[1];
    const float* V = (const float*)d_in[2];
    float* out = (float*)d_out;

    unsigned short* Qb = (unsigned short*)d_ws;            // 4 MB
    unsigned short* Kb = Qb + (size_t)8192 * 256;          // 4 MB
    unsigned short* Vt = Kb + (size_t)8192 * 256;          // 4 MB

    const int n8 = 8192 * 256 / 8;  // 262144
    cvt_bf16_kernel<<<n8 / 256, 256, 0, stream>>>(Q, Qb, 0.0625f, n8);
    cvt_bf16_kernel<<<n8 / 256, 256, 0, stream>>>(K, Kb, 1.0f, n8);
    transpose_v_kernel<<<dim3(128, 4), 256, 0, stream>>>(V, Vt);
    attn_kernel<<<256, 256, 0, stream>>>(Qb, Kb, Vt, out);
}